// Round 10
// baseline (141.504 us; speedup 1.0000x reference)
//
#include <hip/hip_runtime.h>

typedef __bf16 bf16x8 __attribute__((ext_vector_type(8)));
typedef float f32x4 __attribute__((ext_vector_type(4)));
typedef float f32x16 __attribute__((ext_vector_type(16)));
typedef unsigned short u16;
typedef unsigned int u32;

#define TLEN 512
#define DMODEL 512
#define DH 64
#define KVLEN 1152
#define TOTALMEM 640

__device__ inline u16 f2b(float f) {
    union { float f; u32 u; } x; x.f = f;
    u32 u = x.u;
    return (u16)((u + 0x7FFFu + ((u >> 16) & 1u)) >> 16);
}

__device__ inline float wave_red_sum(float v) {
#pragma unroll
    for (int off = 1; off < 64; off <<= 1) v += __shfl_xor(v, off);
    return v;
}

__device__ inline void gload16(const u16* g, u16* l) {
    __builtin_amdgcn_global_load_lds((const __attribute__((address_space(1))) void*)g,
                                     (__attribute__((address_space(3))) void*)l, 16, 0, 0);
}

__device__ __forceinline__ u32 cvtpk_bf16(float lo, float hi) {
    u32 r;
    asm("v_cvt_pk_bf16_f32 %0, %1, %2" : "=v"(r) : "v"(lo), "v"(hi));
    return r;
}

// ---------------- fused prep: kvin + new_mem + weight converts (incl. deconv_w) + acc zero
__global__ __launch_bounds__(256)
void prep_kernel(const float* __restrict__ x, const float* __restrict__ mem,
                 const float* __restrict__ cmem, const float* __restrict__ Wq,
                 const float* __restrict__ Wkv, const float* __restrict__ Wo,
                 const float* __restrict__ cw, const float* __restrict__ dw,
                 u16* __restrict__ kvin, u16* __restrict__ wq_b, u16* __restrict__ wkv_b,
                 u16* __restrict__ wo_b, u16* __restrict__ cw2, u16* __restrict__ dwb,
                 float* __restrict__ newmem, float* __restrict__ accs) {
    int idx = blockIdx.x * 256 + threadIdx.x;
    if (idx == 0) { accs[0] = 0.f; accs[1] = 0.f; accs[2] = 0.f; accs[3] = 0.f; }
    int e = idx * 4;
    float4 v;
    u16* o;
    if (e < 4718592) {
        int row = e >> 9, col = e & 511;
        int b = row / KVLEN, p = row - b * KVLEN;
        const float* src;
        if (p < 128)       src = cmem + ((size_t)(b * 128 + p)) * 512 + col;
        else if (p < 640)  src = mem  + ((size_t)(b * 512 + (p - 128))) * 512 + col;
        else               src = x    + ((size_t)(b * 512 + (p - 640))) * 512 + col;
        v = *(const float4*)src;
        o = kvin + e;
        if (p >= 640)
            *(float4*)(newmem + ((size_t)(b * 512 + (p - 640)) * 512 + col)) = v;
    } else if (e < 4980736) {
        int t = e - 4718592; v = *(const float4*)(Wq + t); o = wq_b + t;
    } else if (e < 5505024) {
        int t = e - 4980736; v = *(const float4*)(Wkv + t); o = wkv_b + t;
    } else if (e < 5767168) {
        int t = e - 5505024; v = *(const float4*)(Wo + t); o = wo_b + t;
    } else if (e < 6815744) {
        int t = e - 5767168;
        int oo = t >> 11, rem = t & 2047, tt = rem >> 9, ii = rem & 511;
        const float* s0 = cw + oo * 2048 + tt;
        v.x = s0[(ii + 0) * 4]; v.y = s0[(ii + 1) * 4];
        v.z = s0[(ii + 2) * 4]; v.w = s0[(ii + 3) * 4];
        o = cw2 + t;
    } else {
        int t = e - 6815744;   // deconv_w 512x128
        v = *(const float4*)(dw + t); o = dwb + t;
    }
    o[0] = f2b(v.x); o[1] = f2b(v.y); o[2] = f2b(v.z); o[3] = f2b(v.w);
}

// ---------------- generic bf16 MFMA GEMM device body (m97 staging)
__device__ __forceinline__ void gemm_dev(
    const u16* __restrict__ A, int lda, int rowsPerB, long long bstride,
    const u16* __restrict__ Bt, int ldb, int Kb,
    float* __restrict__ Cf, u16* __restrict__ Cb, int ldc,
    const float* __restrict__ bias,
    int bx, int by, u16* As, u16* Bs) {
    const int tid = threadIdx.x;
    const int lane = tid & 63, wave = tid >> 6;
    const int wr = (wave >> 1) * 64, wc = (wave & 1) * 64;
    const int fr = lane & 15, fg = lane >> 4;
    const int arow0 = bx * 128;
    const int brow0 = by * 128;

    const int lrow = lane >> 2;
    const int lcol = (lane & 3) * 8;
    const u16* gA[2]; const u16* gB[2];
#pragma unroll
    for (int i = 0; i < 2; ++i) {
        int r = wave * 32 + i * 16 + lrow;
        int gr = arow0 + r;
        int bb = gr / rowsPerB;
        int lr = gr - bb * rowsPerB;
        gA[i] = A + (size_t)bb * bstride + (size_t)lr * lda + lcol;
        gB[i] = Bt + (size_t)(brow0 + r) * ldb + lcol;
    }
    u16* lA0 = &As[(wave * 32) * 32];
    u16* lA1 = &As[(wave * 32 + 16) * 32];
    u16* lB0 = &Bs[(wave * 32) * 32];
    u16* lB1 = &Bs[(wave * 32 + 16) * 32];

    f32x4 acc[4][4] = {};
    for (int k = 0; k < Kb; k += 32) {
        __syncthreads();
        gload16(gA[0] + k, lA0);
        gload16(gA[1] + k, lA1);
        gload16(gB[0] + k, lB0);
        gload16(gB[1] + k, lB1);
        __syncthreads();
        bf16x8 af[4], bfr[4];
#pragma unroll
        for (int m = 0; m < 4; ++m) af[m] = *(bf16x8*)&As[(wr + m * 16 + fr) * 32 + fg * 8];
#pragma unroll
        for (int n = 0; n < 4; ++n) bfr[n] = *(bf16x8*)&Bs[(wc + n * 16 + fr) * 32 + fg * 8];
#pragma unroll
        for (int m = 0; m < 4; ++m)
#pragma unroll
            for (int n = 0; n < 4; ++n)
                acc[m][n] = __builtin_amdgcn_mfma_f32_16x16x32_bf16(af[m], bfr[n], acc[m][n], 0, 0, 0);
    }

#pragma unroll
    for (int m = 0; m < 4; ++m)
#pragma unroll
        for (int n = 0; n < 4; ++n)
#pragma unroll
            for (int r = 0; r < 4; ++r) {
                int row = arow0 + wr + m * 16 + fg * 4 + r;
                int col = brow0 + wc + n * 16 + fr;
                float v = acc[m][n][r];
                if (bias) v += bias[col];
                if (Cf) Cf[(size_t)row * ldc + col] = v;
                if (Cb) Cb[(size_t)row * ldc + col] = f2b(v);
            }
}

// ---------------- fused conv(full-K) + q + kv GEMMs (736 blocks, conv first)
__global__ __launch_bounds__(256)
void gemm3(const u16* __restrict__ kvin, const u16* __restrict__ wq,
           const u16* __restrict__ wkv, const u16* __restrict__ cw2,
           const float* __restrict__ conv_b,
           u16* __restrict__ q_bf, u16* __restrict__ kv_bf,
           float* __restrict__ newcmem, u16* __restrict__ comp_bf) {
    __shared__ u16 As[128 * 32];
    __shared__ u16 Bs[128 * 32];
    int id = blockIdx.x;
    if (id < 32) {
        // conv compression, full K=2048: new_cmem f32 + comp bf16, bias fused
        gemm_dev(kvin + 65536, 2048, 128, 589824, cw2, 2048, 2048,
                 newcmem, comp_bf, 512, conv_b, id & 7, id >> 3, As, Bs);
    } else if (id < 160) {
        int t = id - 32;
        gemm_dev(kvin + 327680, 512, 512, 589824, wq, 512, 512,
                 nullptr, q_bf, 512, nullptr, t & 31, t >> 5, As, Bs);
    } else {
        int t = id - 160;
        gemm_dev(kvin, 512, 9216, 0, wkv, 512, 512,
                 nullptr, kv_bf, 1024, nullptr, t % 72, t / 72, As, Bs);
    }
}

// ---------------- transpose helpers
__device__ __forceinline__ void transpose_dev(const u16* __restrict__ kv,
                                              u16* __restrict__ vT, int rowsPerB,
                                              int jt, int bh, u16* t_s) {
    int b = bh >> 3, h = bh & 7;
    int tid = threadIdx.x;
    int jr = tid >> 2, c0 = (tid & 3) * 16;
    const u16* g = kv + (size_t)(b * rowsPerB + jt * 64 + jr) * 1024 + 512 + h * DH + c0;
#pragma unroll
    for (int u = 0; u < 16; ++u) t_s[jr * 65 + c0 + u] = g[u];
    __syncthreads();
    int dh = tid >> 2, j0 = (tid & 3) * 16;
    union { u16 us[8]; bf16x8 v8; } o1, o2;
#pragma unroll
    for (int u = 0; u < 8; ++u) {
        o1.us[u] = t_s[(j0 + u) * 65 + dh];
        o2.us[u] = t_s[(j0 + 8 + u) * 65 + dh];
    }
    u16* o = vT + (size_t)(bh * DH + dh) * rowsPerB + jt * 64 + j0;
    *(bf16x8*)o = o1.v8;
    *(bf16x8*)(o + 8) = o2.v8;
}

// ---------------- mid: ckv GEMM + compT transpose + vTm transpose (one dispatch)
__global__ __launch_bounds__(256)
void mid_kernel(const u16* __restrict__ comp, const u16* __restrict__ wkv,
                u16* __restrict__ ckv, u16* __restrict__ compT,
                const u16* __restrict__ kv, u16* __restrict__ vTm_) {
    __shared__ __align__(16) char smem[16640];
    int id = blockIdx.x;
    int tid = threadIdx.x;
    if (id < 64) {
        // ckv projection (longest blocks -> scheduled first)
        u16* As = (u16*)smem;
        u16* Bs = (u16*)(smem + 8192);
        gemm_dev(comp, 512, 1024, 0, wkv, 512, 512,
                 nullptr, ckv, 1024, nullptr, id & 7, id >> 3, As, Bs);
        return;
    }
    u16* t_s = (u16*)smem;
    if (id < 192) {
        // comp [b:128 x 512] -> compT [b:512 x 128], 64x64 tiles
        int idq = id - 64;
        int b = idq >> 4, tile = idq & 15;
        int rt = tile >> 3, ct = tile & 7;
        int jr = tid >> 2, c0 = (tid & 3) * 16;
        const u16* g = comp + (size_t)(b * 128 + rt * 64 + jr) * 512 + ct * 64 + c0;
#pragma unroll
        for (int u = 0; u < 16; ++u) t_s[jr * 65 + c0 + u] = g[u];
        __syncthreads();
        int dh = tid >> 2, j0 = (tid & 3) * 16;
        union { u16 us[8]; bf16x8 v8; } o1, o2;
#pragma unroll
        for (int u = 0; u < 8; ++u) {
            o1.us[u] = t_s[(j0 + u) * 65 + dh];
            o2.us[u] = t_s[(j0 + 8 + u) * 65 + dh];
        }
        u16* o = compT + (size_t)(b * 512 + ct * 64 + dh) * 128 + rt * 64 + j0;
        *(bf16x8*)o = o1.v8;
        *(bf16x8*)(o + 8) = o2.v8;
        return;
    }
    // vTm transpose: 1152 blocks
    int t = id - 192;
    transpose_dev(kv, vTm_, KVLEN, t % 18, t / 18, t_s);
}

// ---------------- vTc transpose (needs ckv)
__global__ __launch_bounds__(256)
void vtc_kernel(const u16* __restrict__ ckv, u16* __restrict__ vTc_) {
    __shared__ u16 t_s[64 * 65];
    transpose_dev(ckv, vTc_, 128, blockIdx.x & 1, blockIdx.x >> 1, t_s);
}

// ================= attention: swapped-QK, in-register softmax =================
template <bool MASK>
__device__ __forceinline__ void attn_pass(
    const u16* __restrict__ kbase, int kstride,
    const u16* __restrict__ vbase, int vstride,
    int njt, int tid, int iq_min,
    const bf16x8* qf, u16* k_s, u16* v_s,
    f32x16& o0, f32x16& o1, float& m_run, float& l_run)
{
    const int lane = tid & 63;
    const int c31 = lane & 31;
    const int hi = lane >> 5;
    const int hi4 = hi << 2;
    const int srow = tid >> 2, ssl = tid & 3;
    const int kwa = srow * 64 + ((ssl ^ (srow & 7)) << 3);
    const int kwb = srow * 64 + (((ssl + 4) ^ (srow & 7)) << 3);
    const int iq = iq_min + c31;

    int krd[2][4];
#pragma unroll
    for (int jsub = 0; jsub < 2; ++jsub) {
        int row = jsub * 32 + c31;
#pragma unroll
        for (int ks = 0; ks < 4; ++ks)
            krd[jsub][ks] = row * 64 + (((2 * ks + hi) ^ (row & 7)) << 3);
    }
    int vrd[2][4];
#pragma unroll
    for (int half = 0; half < 2; ++half) {
        int row = half * 32 + c31;
#pragma unroll
        for (int s = 0; s < 4; ++s)
            vrd[half][s] = row * 64 + (((2 * s + hi) ^ (row & 7)) << 3);
    }

    float4 lk0, lk1, lv0, lv1;
#define AT_LOAD(T) { \
        const u16* gk = kbase + (size_t)((T) * 64 + srow) * kstride + ssl * 8; \
        lk0 = *(const float4*)gk; lk1 = *(const float4*)(gk + 32); \
        const u16* gv = vbase + (size_t)srow * vstride + (T) * 64 + ssl * 8; \
        lv0 = *(const float4*)gv; lv1 = *(const float4*)(gv + 32); }
#define AT_STORE(B) { \
        u16* kd = k_s + (B) * 4096; u16* vd = v_s + (B) * 4096; \
        *(float4*)(kd + kwa) = lk0; *(float4*)(kd + kwb) = lk1; \
        *(float4*)(vd + kwa) = lv0; *(float4*)(vd + kwb) = lv1; }

    AT_LOAD(0); AT_STORE(0);
    __syncthreads();

    for (int t = 0; t < njt; ++t) {
        const int cur = t & 1;
        if (t + 1 < njt) AT_LOAD(t + 1);
        const u16* ks_ = k_s + cur * 4096;
        const u16* vs_ = v_s + cur * 4096;

        f32x16 sA = {}, sB = {};
#pragma unroll
        for (int ks = 0; ks < 4; ++ks) {
            bf16x8 a0 = *(const bf16x8*)&ks_[krd[0][ks]];
            sA = __builtin_amdgcn_mfma_f32_32x32x16_bf16(a0, qf[ks], sA, 0, 0, 0);
        }
#pragma unroll
        for (int ks = 0; ks < 4; ++ks) {
            bf16x8 a1 = *(const bf16x8*)&ks_[krd[1][ks]];
            sB = __builtin_amdgcn_mfma_f32_32x32x16_bf16(a1, qf[ks], sB, 0, 0, 0);
        }
        if (MASK) {
            if (t * 64 + 63 > iq_min + TOTALMEM) {
#pragma unroll
                for (int r = 0; r < 16; ++r) {
                    int rj = (r & 3) + 8 * (r >> 2) + hi4;
                    if (t * 64 + rj > iq + TOTALMEM) sA[r] = -1e30f;
                    if (t * 64 + 32 + rj > iq + TOTALMEM) sB[r] = -1e30f;
                }
            }
        }
        float tmax = sA[0];
#pragma unroll
        for (int r = 1; r < 16; ++r) tmax = fmaxf(tmax, sA[r]);
#pragma unroll
        for (int r = 0; r < 16; ++r) tmax = fmaxf(tmax, sB[r]);
        tmax = fmaxf(tmax, __shfl_xor(tmax, 32));
        tmax *= 0.125f;
        if (__any(tmax > m_run + 8.0f)) {
            float m_new = fmaxf(m_run, tmax);
            float scl = __expf(m_run - m_new);
            m_run = m_new;
            l_run *= scl;
#pragma unroll
            for (int r = 0; r < 16; ++r) {
                float sc = __shfl(scl, (r & 3) + 8 * (r >> 2) + hi4);
                o0[r] *= sc; o1[r] *= sc;
            }
        }
        const float negm = -m_run;
        float ps = 0.f;
#pragma unroll
        for (int jsub = 0; jsub < 2; ++jsub) {
#pragma unroll
            for (int ksub = 0; ksub < 2; ++ksub) {
                float p0 = __expf(fmaf((jsub ? sB[ksub * 8 + 0] : sA[ksub * 8 + 0]), 0.125f, negm));
                float p1 = __expf(fmaf((jsub ? sB[ksub * 8 + 1] : sA[ksub * 8 + 1]), 0.125f, negm));
                float p2 = __expf(fmaf((jsub ? sB[ksub * 8 + 2] : sA[ksub * 8 + 2]), 0.125f, negm));
                float p3 = __expf(fmaf((jsub ? sB[ksub * 8 + 3] : sA[ksub * 8 + 3]), 0.125f, negm));
                float p4 = __expf(fmaf((jsub ? sB[ksub * 8 + 4] : sA[ksub * 8 + 4]), 0.125f, negm));
                float p5 = __expf(fmaf((jsub ? sB[ksub * 8 + 5] : sA[ksub * 8 + 5]), 0.125f, negm));
                float p6 = __expf(fmaf((jsub ? sB[ksub * 8 + 6] : sA[ksub * 8 + 6]), 0.125f, negm));
                float p7 = __expf(fmaf((jsub ? sB[ksub * 8 + 7] : sA[ksub * 8 + 7]), 0.125f, negm));
                ps += ((p0 + p1) + (p2 + p3)) + ((p4 + p5) + (p6 + p7));
                u32 X = cvtpk_bf16(p0, p1);
                u32 Z = cvtpk_bf16(p2, p3);
                u32 Y = cvtpk_bf16(p4, p5);
                u32 W = cvtpk_bf16(p6, p7);
                auto s1 = __builtin_amdgcn_permlane32_swap(X, Y, false, false);
                auto s2 = __builtin_amdgcn_permlane32_swap(Z, W, false, false);
                union { u32 w[4]; bf16x8 v; } fa;
                fa.w[0] = (u32)s1[0]; fa.w[1] = (u32)s2[0];
                fa.w[2] = (u32)s1[1]; fa.w[3] = (u32)s2[1];
                bf16x8 bv0 = *(const bf16x8*)&vs_[vrd[0][jsub * 2 + ksub]];
                bf16x8 bv1 = *(const bf16x8*)&vs_[vrd[1][jsub * 2 + ksub]];
                o0 = __builtin_amdgcn_mfma_f32_32x32x16_bf16(fa.v, bv0, o0, 0, 0, 0);
                o1 = __builtin_amdgcn_mfma_f32_32x32x16_bf16(fa.v, bv1, o1, 0, 0, 0);
            }
        }
        ps += __shfl_xor(ps, 32);
        l_run += ps;
        if (t + 1 < njt) AT_STORE(cur ^ 1);
        __syncthreads();
    }
#undef AT_LOAD
#undef AT_STORE
}

// ---------------- fused main + aux attention (512 blocks -> 2 waves/SIMD)
__global__ __launch_bounds__(256)
void attn_fused(const u16* __restrict__ q_bf, const u16* __restrict__ kv,
                const u16* __restrict__ vTm_, const u16* __restrict__ ckv,
                const u16* __restrict__ vTc_, u16* __restrict__ out_bf,
                float* __restrict__ acc_sum) {
    __shared__ u16 k_s[2 * 4096];
    __shared__ u16 v_s[2 * 4096];
    __shared__ float red_s[4];
    const int id = blockIdx.x;
    const int tid = threadIdx.x;
    const int w = tid >> 6, lane = tid & 63;
    const int c31 = lane & 31, hi4 = (lane >> 5) << 2;

    if (id < 256) {
        const int it = id & 3, bh = id >> 2;
        const int b = bh >> 3, h = bh & 7;
        const int iwmin = it * 128 + w * 32;
        const int iq = iwmin + c31;

        bf16x8 qf[4];
#pragma unroll
        for (int ks = 0; ks < 4; ++ks)
            qf[ks] = *(const bf16x8*)&q_bf[(size_t)(b * TLEN + iq) * DMODEL + h * DH + ks * 16 + hi4 * 2];

        const u16* kbase = kv + (size_t)b * KVLEN * 1024 + h * DH;
        const u16* vbase = vTm_ + (size_t)(bh * DH) * KVLEN;
        const int njt = ((it * 128 + 767) >> 6) + 1;

        f32x16 o0 = {}, o1 = {};
        float m_run = -1e30f, l_run = 0.f;
        attn_pass<true>(kbase, 1024, vbase, KVLEN, njt, tid, iwmin, qf, k_s, v_s, o0, o1, m_run, l_run);

        float linv = 1.0f / l_run;
#pragma unroll
        for (int r = 0; r < 16; ++r) {
            int R = (r & 3) + 8 * (r >> 2) + hi4;
            float li = __shfl(linv, R);
            int i = iwmin + R;
            u16* o = out_bf + (size_t)(b * TLEN + i) * DMODEL + h * DH + c31;
            o[0]  = f2b(o0[r] * li);
            o[32] = f2b(o1[r] * li);
        }
    } else {
        const int t2 = id - 256;
        const int it = t2 & 3, bh = t2 >> 2;
        const int b = bh >> 3, h = bh & 7;
        const int iwmin = it * 128 + w * 32;
        const int iq = iwmin + c31;

        bf16x8 qf[4];
#pragma unroll
        for (int ks = 0; ks < 4; ++ks)
            qf[ks] = *(const bf16x8*)&q_bf[(size_t)(b * TLEN + iq) * DMODEL + h * DH + ks * 16 + hi4 * 2];

        f32x16 o0 = {}, o1 = {};
        float m_run = -1e30f, l_run = 0.f;
        attn_pass<false>(kv + (size_t)(b * KVLEN + 128) * 1024 + h * DH, 1024,
                         vTm_ + (size_t)(bh * DH) * KVLEN + 128, KVLEN, 8,
                         tid, 0, qf, k_s, v_s, o0, o1, m_run, l_run);
        float n0[16], n1[16];
        {
            float linv = 1.0f / l_run;
#pragma unroll
            for (int r = 0; r < 16; ++r) {
                float li = __shfl(linv, (r & 3) + 8 * (r >> 2) + hi4);
                n0[r] = o0[r] * li;
                n1[r] = o1[r] * li;
            }
        }
        f32x16 c0 = {}, c1 = {};
        m_run = -1e30f; l_run = 0.f;
        attn_pass<false>(ckv + (size_t)(b * 128) * 1024 + h * DH, 1024,
                         vTc_ + (size_t)(bh * DH) * 128, 128, 2,
                         tid, 0, qf, k_s, v_s, c0, c1, m_run, l_run);
        float lsum = 0.f;
        {
            float linv = 1.0f / l_run;
#pragma unroll
            for (int r = 0; r < 16; ++r) {
                float li = __shfl(linv, (r & 3) + 8 * (r >> 2) + hi4);
                float d0 = n0[r] - c0[r] * li;
                float d1 = n1[r] - c1[r] * li;
                lsum += d0 * d0 + d1 * d1;
            }
        }
        lsum = wave_red_sum(lsum);
        if (lane == 0) red_s[w] = lsum;
        __syncthreads();
        if (tid == 0) atomicAdd(acc_sum, red_s[0] + red_s[1] + red_s[2] + red_s[3]);
    }
}

// ---------------- fused tail: Wo GEMM + ae loss as MFMA GEMM w/ diff^2 epilogue + finalize
__global__ __launch_bounds__(256)
void tail2(const u16* __restrict__ attn_bf, const u16* __restrict__ wo_b,
           const float* __restrict__ bo, float* __restrict__ logits,
           const u16* __restrict__ dwb, const u16* __restrict__ compT,
           const float* __restrict__ mem, const float* __restrict__ db,
           float* __restrict__ accs, float* __restrict__ scal_out) {
    __shared__ __align__(16) char smem[16400];
    const int id = blockIdx.x;
    const int tid = threadIdx.x;
    u16* As = (u16*)smem;
    u16* Bs = (u16*)(smem + 8192);

    if (id < 128) {
        gemm_dev(attn_bf, 512, 4096, 0, wo_b, 512, 512,
                 logits, nullptr, 512, bo, id & 31, id >> 5, As, Bs);
        return;
    }
    // ---- ae loss: recon = dw(512x128) x compT^T(512x128) per b, diff^2 vs mem, no C write
    float* red = (float*)(smem + 16384);
    const int t = id - 128;              // 0..127
    const int b = t >> 4;
    const int bx = (t >> 2) & 3, by = t & 3;
    const int lane = tid & 63, wave = tid >> 6;
    const int wr = (wave >> 1) * 64, wc = (wave & 1) * 64;
    const int fr = lane & 15, fg = lane >> 4;
    const int arow0 = bx * 128, brow0 = by * 128;
    const int lrow = lane >> 2, lcol = (lane & 3) * 8;
    const u16* gA[2]; const u16* gB[2];
#pragma unroll
    for (int i = 0; i < 2; ++i) {
        int r = wave * 32 + i * 16 + lrow;
        gA[i] = dwb + (size_t)(arow0 + r) * 128 + lcol;
        gB[i] = compT + (size_t)(b * 512 + brow0 + r) * 128 + lcol;
    }
    u16* lA0 = &As[(wave * 32) * 32];
    u16* lA1 = &As[(wave * 32 + 16) * 32];
    u16* lB0 = &Bs[(wave * 32) * 32];
    u16* lB1 = &Bs[(wave * 32 + 16) * 32];

    f32x4 acc[4][4] = {};
    for (int k = 0; k < 128; k += 32) {
        __syncthreads();
        gload16(gA[0] + k, lA0);
        gload16(gA[1] + k, lA1);
        gload16(gB[0] + k, lB0);
        gload16(gB[1] + k, lB1);
        __syncthreads();
        bf16x8 af[4], bfr[4];
#pragma unroll
        for (int m = 0; m < 4; ++m) af[m] = *(bf16x8*)&As[(wr + m * 16 + fr) * 32 + fg * 8];
#pragma unroll
        for (int n = 0; n < 4; ++n) bfr[n] = *(bf16x8*)&Bs[(wc + n * 16 + fr) * 32 + fg * 8];
#pragma unroll
        for (int m = 0; m < 4; ++m)
#pragma unroll
            for (int n = 0; n < 4; ++n)
                acc[m][n] = __builtin_amdgcn_mfma_f32_16x16x32_bf16(af[m], bfr[n], acc[m][n], 0, 0, 0);
    }

    float lsum = 0.f;
#pragma unroll
    for (int m = 0; m < 4; ++m)
#pragma unroll
        for (int n = 0; n < 4; ++n)
#pragma unroll
            for (int rr = 0; rr < 4; ++rr) {
                int row = arow0 + wr + m * 16 + fg * 4 + rr;   // mem row m
                int col = brow0 + wc + n * 16 + fr;            // dd
                float v = acc[m][n][rr] + db[row];
                float d = mem[(size_t)(b * 512 + row) * 512 + col] - v;
                lsum = fmaf(d, d, lsum);
            }
    lsum = wave_red_sum(lsum);
    if (lane == 0) red[wave] = lsum;
    __syncthreads();
    if (tid == 0) {
        atomicAdd(accs + 1, red[0] + red[1] + red[2] + red[3]);
        __threadfence();
        u32 c = atomicAdd((u32*)(accs + 2), 1u);
        if (c == 127u) {
            float a0 = atomicAdd(accs + 0, 0.f);
            float a1 = atomicAdd(accs + 1, 0.f);
            scal_out[0] = a0 * (1.f / 2097152.f);
            scal_out[1] = a1 * (1.f / 2097152.f);
        }
    }
}

// ---------------- launch ----------------
extern "C" void kernel_launch(void* const* d_in, const int* in_sizes, int n_in,
                              void* d_out, int out_size, void* d_ws, size_t ws_size,
                              hipStream_t stream) {
    const float* x      = (const float*)d_in[0];
    const float* mem    = (const float*)d_in[1];
    const float* cmem   = (const float*)d_in[2];
    const float* Wq     = (const float*)d_in[3];
    const float* Wkv    = (const float*)d_in[4];
    const float* Wo     = (const float*)d_in[5];
    const float* bo     = (const float*)d_in[6];
    const float* conv_w = (const float*)d_in[7];
    const float* conv_b = (const float*)d_in[8];
    const float* deconv_w = (const float*)d_in[9];
    const float* deconv_b = (const float*)d_in[10];
    float* out = (float*)d_out;

    char* w = (char*)d_ws;
    auto alloc = [&](size_t bytes) { char* p = w; w += (bytes + 255) & ~255ull; return p; };
    u16* Wq_bf   = (u16*)alloc(262144 * 2);
    u16* Wkv_bf  = (u16*)alloc(524288 * 2);
    u16* Wo_bf   = (u16*)alloc(262144 * 2);
    u16* cw2_bf  = (u16*)alloc(1048576 * 2);
    u16* dwb_bf  = (u16*)alloc(65536 * 2);
    u16* kvin_bf = (u16*)alloc(4718592 * 2);
    u16* q_bf    = (u16*)alloc(2097152 * 2);
    u16* kv_bf   = (u16*)alloc(9437184 * 2);
    u16* comp_bf = (u16*)alloc(524288 * 2);
    u16* compT   = (u16*)alloc(524288 * 2);
    u16* ckv_bf  = (u16*)alloc(1048576 * 2);
    u16* vTm     = (u16*)alloc(4718592 * 2);
    u16* vTc     = (u16*)alloc(524288 * 2);
    u16* attn_bf = (u16*)alloc(2097152 * 2);
    float* accs  = (float*)alloc(256);

    float* logits_o  = out;
    float* newmem_o  = out + 2097152;
    float* newcmem_o = out + 4194304;
    float* scalars_o = out + 4718592;

    // 1. prep: kvin + new_mem + weight converts (+deconv_w) + acc zero
    prep_kernel<<<6720, 256, 0, stream>>>(x, mem, cmem, Wq, Wkv, Wo, conv_w, deconv_w,
                                          kvin_bf, Wq_bf, Wkv_bf, Wo_bf, cw2_bf, dwb_bf,
                                          newmem_o, accs);

    // 2. fused conv(full-K, first) + q + kv GEMMs (736 blocks)
    gemm3<<<736, 256, 0, stream>>>(kvin_bf, Wq_bf, Wkv_bf, cw2_bf, conv_b,
                                   q_bf, kv_bf, newcmem_o, comp_bf);

    // 3. mid: ckv GEMM + compT + vTm transposes (1344 blocks)
    mid_kernel<<<1344, 256, 0, stream>>>(comp_bf, Wkv_bf, ckv_bf, compT, kv_bf, vTm);

    // 4. vTc transpose (needs ckv)
    vtc_kernel<<<128, 256, 0, stream>>>(ckv_bf, vTc);

    // 5. fused main + aux attention
    attn_fused<<<512, 256, 0, stream>>>(q_bf, kv_bf, vTm, ckv_bf, vTc, attn_bf, accs);

    // 6. fused tail: Wo GEMM + ae-loss MFMA GEMM + finalize
    tail2<<<256, 256, 0, stream>>>(attn_bf, Wo_bf, bo, logits_o,
                                   dwb_bf, compT, mem, deconv_b,
                                   accs, scalars_o);
}

// Round 11
// 115.123 us; speedup vs baseline: 1.2292x; 1.2292x over previous
//
#include <hip/hip_runtime.h>

typedef __bf16 bf16x8 __attribute__((ext_vector_type(8)));
typedef float f32x4 __attribute__((ext_vector_type(4)));
typedef float f32x16 __attribute__((ext_vector_type(16)));
typedef unsigned short u16;
typedef unsigned int u32;

#define TLEN 512
#define DMODEL 512
#define DH 64
#define KVLEN 1152
#define TOTALMEM 640

__device__ inline u16 f2b(float f) {
    union { float f; u32 u; } x; x.f = f;
    u32 u = x.u;
    return (u16)((u + 0x7FFFu + ((u >> 16) & 1u)) >> 16);
}

__device__ inline float wave_red_sum(float v) {
#pragma unroll
    for (int off = 1; off < 64; off <<= 1) v += __shfl_xor(v, off);
    return v;
}

__device__ inline void gload16(const u16* g, u16* l) {
    __builtin_amdgcn_global_load_lds((const __attribute__((address_space(1))) void*)g,
                                     (__attribute__((address_space(3))) void*)l, 16, 0, 0);
}

__device__ __forceinline__ u32 cvtpk_bf16(float lo, float hi) {
    u32 r;
    asm("v_cvt_pk_bf16_f32 %0, %1, %2" : "=v"(r) : "v"(lo), "v"(hi));
    return r;
}

// ---------------- fused prep: kvin + new_mem + weight converts (incl. deconv_w) + acc zero
__global__ __launch_bounds__(256)
void prep_kernel(const float* __restrict__ x, const float* __restrict__ mem,
                 const float* __restrict__ cmem, const float* __restrict__ Wq,
                 const float* __restrict__ Wkv, const float* __restrict__ Wo,
                 const float* __restrict__ cw, const float* __restrict__ dw,
                 u16* __restrict__ kvin, u16* __restrict__ wq_b, u16* __restrict__ wkv_b,
                 u16* __restrict__ wo_b, u16* __restrict__ cw2, u16* __restrict__ dwb,
                 float* __restrict__ newmem, float* __restrict__ accs) {
    int idx = blockIdx.x * 256 + threadIdx.x;
    if (idx == 0) { accs[0] = 0.f; accs[1] = 0.f; accs[2] = 0.f; accs[3] = 0.f; }
    int e = idx * 4;
    float4 v;
    u16* o;
    if (e < 4718592) {
        int row = e >> 9, col = e & 511;
        int b = row / KVLEN, p = row - b * KVLEN;
        const float* src;
        if (p < 128)       src = cmem + ((size_t)(b * 128 + p)) * 512 + col;
        else if (p < 640)  src = mem  + ((size_t)(b * 512 + (p - 128))) * 512 + col;
        else               src = x    + ((size_t)(b * 512 + (p - 640))) * 512 + col;
        v = *(const float4*)src;
        o = kvin + e;
        if (p >= 640)
            *(float4*)(newmem + ((size_t)(b * 512 + (p - 640)) * 512 + col)) = v;
    } else if (e < 4980736) {
        int t = e - 4718592; v = *(const float4*)(Wq + t); o = wq_b + t;
    } else if (e < 5505024) {
        int t = e - 4980736; v = *(const float4*)(Wkv + t); o = wkv_b + t;
    } else if (e < 5767168) {
        int t = e - 5505024; v = *(const float4*)(Wo + t); o = wo_b + t;
    } else if (e < 6815744) {
        int t = e - 5767168;
        int oo = t >> 11, rem = t & 2047, tt = rem >> 9, ii = rem & 511;
        const float* s0 = cw + oo * 2048 + tt;
        v.x = s0[(ii + 0) * 4]; v.y = s0[(ii + 1) * 4];
        v.z = s0[(ii + 2) * 4]; v.w = s0[(ii + 3) * 4];
        o = cw2 + t;
    } else {
        int t = e - 6815744;   // deconv_w 512x128
        v = *(const float4*)(dw + t); o = dwb + t;
    }
    o[0] = f2b(v.x); o[1] = f2b(v.y); o[2] = f2b(v.z); o[3] = f2b(v.w);
}

// ---------------- generic bf16 MFMA GEMM device body (m97 staging, optional split-K)
__device__ __forceinline__ void gemm_dev(
    const u16* __restrict__ A, int lda, int rowsPerB, long long bstride,
    const u16* __restrict__ Bt, int ldb, int Kb,
    float* __restrict__ Cpart, int partStride,
    float* __restrict__ Cf, u16* __restrict__ Cb, int ldc,
    const float* __restrict__ bias,
    int bx, int by, int bz, u16* As, u16* Bs) {
    const int tid = threadIdx.x;
    const int lane = tid & 63, wave = tid >> 6;
    const int wr = (wave >> 1) * 64, wc = (wave & 1) * 64;
    const int fr = lane & 15, fg = lane >> 4;
    const int arow0 = bx * 128;
    const int brow0 = by * 128;
    const int k0start = bz * Kb;

    const int lrow = lane >> 2;
    const int lcol = (lane & 3) * 8;
    const u16* gA[2]; const u16* gB[2];
#pragma unroll
    for (int i = 0; i < 2; ++i) {
        int r = wave * 32 + i * 16 + lrow;
        int gr = arow0 + r;
        int bb = gr / rowsPerB;
        int lr = gr - bb * rowsPerB;
        gA[i] = A + (size_t)bb * bstride + (size_t)lr * lda + k0start + lcol;
        gB[i] = Bt + (size_t)(brow0 + r) * ldb + k0start + lcol;
    }
    u16* lA0 = &As[(wave * 32) * 32];
    u16* lA1 = &As[(wave * 32 + 16) * 32];
    u16* lB0 = &Bs[(wave * 32) * 32];
    u16* lB1 = &Bs[(wave * 32 + 16) * 32];

    f32x4 acc[4][4] = {};
    for (int k = 0; k < Kb; k += 32) {
        __syncthreads();
        gload16(gA[0] + k, lA0);
        gload16(gA[1] + k, lA1);
        gload16(gB[0] + k, lB0);
        gload16(gB[1] + k, lB1);
        __syncthreads();
        bf16x8 af[4], bfr[4];
#pragma unroll
        for (int m = 0; m < 4; ++m) af[m] = *(bf16x8*)&As[(wr + m * 16 + fr) * 32 + fg * 8];
#pragma unroll
        for (int n = 0; n < 4; ++n) bfr[n] = *(bf16x8*)&Bs[(wc + n * 16 + fr) * 32 + fg * 8];
#pragma unroll
        for (int m = 0; m < 4; ++m)
#pragma unroll
            for (int n = 0; n < 4; ++n)
                acc[m][n] = __builtin_amdgcn_mfma_f32_16x16x32_bf16(af[m], bfr[n], acc[m][n], 0, 0, 0);
    }

#pragma unroll
    for (int m = 0; m < 4; ++m)
#pragma unroll
        for (int n = 0; n < 4; ++n)
#pragma unroll
            for (int r = 0; r < 4; ++r) {
                int row = arow0 + wr + m * 16 + fg * 4 + r;
                int col = brow0 + wc + n * 16 + fr;
                float v = acc[m][n][r];
                if (Cpart) {
                    Cpart[(size_t)bz * partStride + (size_t)row * ldc + col] = v;
                } else {
                    if (bias) v += bias[col];
                    if (Cf) Cf[(size_t)row * ldc + col] = v;
                    if (Cb) Cb[(size_t)row * ldc + col] = f2b(v);
                }
            }
}

// ---------------- fused q + kv + conv GEMMs (832 blocks, conv split-K=4: r2/r9 lesson)
__global__ __launch_bounds__(256)
void gemm3(const u16* __restrict__ kvin, const u16* __restrict__ wq,
           const u16* __restrict__ wkv, const u16* __restrict__ cw2,
           u16* __restrict__ q_bf, u16* __restrict__ kv_bf, float* __restrict__ part) {
    __shared__ u16 As[128 * 32];
    __shared__ u16 Bs[128 * 32];
    int id = blockIdx.x;
    if (id < 128) {
        gemm_dev(kvin + 327680, 512, 512, 589824, wq, 512, 512,
                 nullptr, 0, nullptr, q_bf, 512, nullptr,
                 id & 31, id >> 5, 0, As, Bs);
    } else if (id < 704) {
        int t = id - 128;
        gemm_dev(kvin, 512, 9216, 0, wkv, 512, 512,
                 nullptr, 0, nullptr, kv_bf, 1024, nullptr,
                 t % 72, t / 72, 0, As, Bs);
    } else {
        int t = id - 704;   // 128 blocks: 8 x 4 x 4 split-K
        gemm_dev(kvin + 65536, 2048, 128, 589824, cw2, 2048, 512,
                 part, 524288, nullptr, nullptr, 512, nullptr,
                 t & 7, (t >> 3) & 3, t >> 5, As, Bs);
    }
}

// ---------------- split-K reduce for conv (4 slices)
__global__ __launch_bounds__(256)
void conv_reduce(const float* __restrict__ part, const float* __restrict__ cb,
                 float* __restrict__ outf, u16* __restrict__ outb) {
    int idx = (blockIdx.x * 256 + threadIdx.x) * 4;
    float4 s = *(const float4*)(part + idx);
#pragma unroll
    for (int sp = 1; sp < 4; ++sp) {
        float4 p = *(const float4*)(part + (size_t)sp * 524288 + idx);
        s.x += p.x; s.y += p.y; s.z += p.z; s.w += p.w;
    }
    float4 bb = *(const float4*)(cb + (idx & 511));
    s.x += bb.x; s.y += bb.y; s.z += bb.z; s.w += bb.w;
    *(float4*)(outf + idx) = s;
    outb[idx + 0] = f2b(s.x); outb[idx + 1] = f2b(s.y);
    outb[idx + 2] = f2b(s.z); outb[idx + 3] = f2b(s.w);
}

// ---------------- transpose helpers
__device__ __forceinline__ void transpose_dev(const u16* __restrict__ kv,
                                              u16* __restrict__ vT, int rowsPerB,
                                              int jt, int bh, u16* t_s) {
    int b = bh >> 3, h = bh & 7;
    int tid = threadIdx.x;
    int jr = tid >> 2, c0 = (tid & 3) * 16;
    const u16* g = kv + (size_t)(b * rowsPerB + jt * 64 + jr) * 1024 + 512 + h * DH + c0;
#pragma unroll
    for (int u = 0; u < 16; ++u) t_s[jr * 65 + c0 + u] = g[u];
    __syncthreads();
    int dh = tid >> 2, j0 = (tid & 3) * 16;
    union { u16 us[8]; bf16x8 v8; } o1, o2;
#pragma unroll
    for (int u = 0; u < 8; ++u) {
        o1.us[u] = t_s[(j0 + u) * 65 + dh];
        o2.us[u] = t_s[(j0 + 8 + u) * 65 + dh];
    }
    u16* o = vT + (size_t)(bh * DH + dh) * rowsPerB + jt * 64 + j0;
    *(bf16x8*)o = o1.v8;
    *(bf16x8*)(o + 8) = o2.v8;
}

// ---------------- mid: ckv GEMM + compT transpose + vTm transpose (one dispatch)
__global__ __launch_bounds__(256)
void mid_kernel(const u16* __restrict__ comp, const u16* __restrict__ wkv,
                u16* __restrict__ ckv, u16* __restrict__ compT,
                const u16* __restrict__ kv, u16* __restrict__ vTm_) {
    __shared__ __align__(16) char smem[16640];
    int id = blockIdx.x;
    int tid = threadIdx.x;
    if (id < 64) {
        u16* As = (u16*)smem;
        u16* Bs = (u16*)(smem + 8192);
        gemm_dev(comp, 512, 1024, 0, wkv, 512, 512,
                 nullptr, 0, nullptr, ckv, 1024, nullptr, id & 7, id >> 3, 0, As, Bs);
        return;
    }
    u16* t_s = (u16*)smem;
    if (id < 192) {
        // comp [b:128 x 512] -> compT [b:512 x 128], 64x64 tiles
        int idq = id - 64;
        int b = idq >> 4, tile = idq & 15;
        int rt = tile >> 3, ct = tile & 7;
        int jr = tid >> 2, c0 = (tid & 3) * 16;
        const u16* g = comp + (size_t)(b * 128 + rt * 64 + jr) * 512 + ct * 64 + c0;
#pragma unroll
        for (int u = 0; u < 16; ++u) t_s[jr * 65 + c0 + u] = g[u];
        __syncthreads();
        int dh = tid >> 2, j0 = (tid & 3) * 16;
        union { u16 us[8]; bf16x8 v8; } o1, o2;
#pragma unroll
        for (int u = 0; u < 8; ++u) {
            o1.us[u] = t_s[(j0 + u) * 65 + dh];
            o2.us[u] = t_s[(j0 + 8 + u) * 65 + dh];
        }
        u16* o = compT + (size_t)(b * 512 + ct * 64 + dh) * 128 + rt * 64 + j0;
        *(bf16x8*)o = o1.v8;
        *(bf16x8*)(o + 8) = o2.v8;
        return;
    }
    // vTm transpose: 1152 blocks
    int t = id - 192;
    transpose_dev(kv, vTm_, KVLEN, t % 18, t / 18, t_s);
}

// ---------------- vTc transpose (needs ckv)
__global__ __launch_bounds__(256)
void vtc_kernel(const u16* __restrict__ ckv, u16* __restrict__ vTc_) {
    __shared__ u16 t_s[64 * 65];
    transpose_dev(ckv, vTc_, 128, blockIdx.x & 1, blockIdx.x >> 1, t_s);
}

// ================= attention: swapped-QK, in-register softmax =================
template <bool MASK>
__device__ __forceinline__ void attn_pass(
    const u16* __restrict__ kbase, int kstride,
    const u16* __restrict__ vbase, int vstride,
    int njt, int tid, int iq_min,
    const bf16x8* qf, u16* k_s, u16* v_s,
    f32x16& o0, f32x16& o1, float& m_run, float& l_run)
{
    const int lane = tid & 63;
    const int c31 = lane & 31;
    const int hi = lane >> 5;
    const int hi4 = hi << 2;
    const int srow = tid >> 2, ssl = tid & 3;
    const int kwa = srow * 64 + ((ssl ^ (srow & 7)) << 3);
    const int kwb = srow * 64 + (((ssl + 4) ^ (srow & 7)) << 3);
    const int iq = iq_min + c31;

    int krd[2][4];
#pragma unroll
    for (int jsub = 0; jsub < 2; ++jsub) {
        int row = jsub * 32 + c31;
#pragma unroll
        for (int ks = 0; ks < 4; ++ks)
            krd[jsub][ks] = row * 64 + (((2 * ks + hi) ^ (row & 7)) << 3);
    }
    int vrd[2][4];
#pragma unroll
    for (int half = 0; half < 2; ++half) {
        int row = half * 32 + c31;
#pragma unroll
        for (int s = 0; s < 4; ++s)
            vrd[half][s] = row * 64 + (((2 * s + hi) ^ (row & 7)) << 3);
    }

    float4 lk0, lk1, lv0, lv1;
#define AT_LOAD(T) { \
        const u16* gk = kbase + (size_t)((T) * 64 + srow) * kstride + ssl * 8; \
        lk0 = *(const float4*)gk; lk1 = *(const float4*)(gk + 32); \
        const u16* gv = vbase + (size_t)srow * vstride + (T) * 64 + ssl * 8; \
        lv0 = *(const float4*)gv; lv1 = *(const float4*)(gv + 32); }
#define AT_STORE(B) { \
        u16* kd = k_s + (B) * 4096; u16* vd = v_s + (B) * 4096; \
        *(float4*)(kd + kwa) = lk0; *(float4*)(kd + kwb) = lk1; \
        *(float4*)(vd + kwa) = lv0; *(float4*)(vd + kwb) = lv1; }

    AT_LOAD(0); AT_STORE(0);
    __syncthreads();

    for (int t = 0; t < njt; ++t) {
        const int cur = t & 1;
        if (t + 1 < njt) AT_LOAD(t + 1);
        const u16* ks_ = k_s + cur * 4096;
        const u16* vs_ = v_s + cur * 4096;

        f32x16 sA = {}, sB = {};
#pragma unroll
        for (int ks = 0; ks < 4; ++ks) {
            bf16x8 a0 = *(const bf16x8*)&ks_[krd[0][ks]];
            sA = __builtin_amdgcn_mfma_f32_32x32x16_bf16(a0, qf[ks], sA, 0, 0, 0);
        }
#pragma unroll
        for (int ks = 0; ks < 4; ++ks) {
            bf16x8 a1 = *(const bf16x8*)&ks_[krd[1][ks]];
            sB = __builtin_amdgcn_mfma_f32_32x32x16_bf16(a1, qf[ks], sB, 0, 0, 0);
        }
        if (MASK) {
            if (t * 64 + 63 > iq_min + TOTALMEM) {
#pragma unroll
                for (int r = 0; r < 16; ++r) {
                    int rj = (r & 3) + 8 * (r >> 2) + hi4;
                    if (t * 64 + rj > iq + TOTALMEM) sA[r] = -1e30f;
                    if (t * 64 + 32 + rj > iq + TOTALMEM) sB[r] = -1e30f;
                }
            }
        }
        float tmax = sA[0];
#pragma unroll
        for (int r = 1; r < 16; ++r) tmax = fmaxf(tmax, sA[r]);
#pragma unroll
        for (int r = 0; r < 16; ++r) tmax = fmaxf(tmax, sB[r]);
        tmax = fmaxf(tmax, __shfl_xor(tmax, 32));
        tmax *= 0.125f;
        if (__any(tmax > m_run + 8.0f)) {
            float m_new = fmaxf(m_run, tmax);
            float scl = __expf(m_run - m_new);
            m_run = m_new;
            l_run *= scl;
#pragma unroll
            for (int r = 0; r < 16; ++r) {
                float sc = __shfl(scl, (r & 3) + 8 * (r >> 2) + hi4);
                o0[r] *= sc; o1[r] *= sc;
            }
        }
        const float negm = -m_run;
        float ps = 0.f;
#pragma unroll
        for (int jsub = 0; jsub < 2; ++jsub) {
#pragma unroll
            for (int ksub = 0; ksub < 2; ++ksub) {
                float p0 = __expf(fmaf((jsub ? sB[ksub * 8 + 0] : sA[ksub * 8 + 0]), 0.125f, negm));
                float p1 = __expf(fmaf((jsub ? sB[ksub * 8 + 1] : sA[ksub * 8 + 1]), 0.125f, negm));
                float p2 = __expf(fmaf((jsub ? sB[ksub * 8 + 2] : sA[ksub * 8 + 2]), 0.125f, negm));
                float p3 = __expf(fmaf((jsub ? sB[ksub * 8 + 3] : sA[ksub * 8 + 3]), 0.125f, negm));
                float p4 = __expf(fmaf((jsub ? sB[ksub * 8 + 4] : sA[ksub * 8 + 4]), 0.125f, negm));
                float p5 = __expf(fmaf((jsub ? sB[ksub * 8 + 5] : sA[ksub * 8 + 5]), 0.125f, negm));
                float p6 = __expf(fmaf((jsub ? sB[ksub * 8 + 6] : sA[ksub * 8 + 6]), 0.125f, negm));
                float p7 = __expf(fmaf((jsub ? sB[ksub * 8 + 7] : sA[ksub * 8 + 7]), 0.125f, negm));
                ps += ((p0 + p1) + (p2 + p3)) + ((p4 + p5) + (p6 + p7));
                u32 X = cvtpk_bf16(p0, p1);
                u32 Z = cvtpk_bf16(p2, p3);
                u32 Y = cvtpk_bf16(p4, p5);
                u32 W = cvtpk_bf16(p6, p7);
                auto s1 = __builtin_amdgcn_permlane32_swap(X, Y, false, false);
                auto s2 = __builtin_amdgcn_permlane32_swap(Z, W, false, false);
                union { u32 w[4]; bf16x8 v; } fa;
                fa.w[0] = (u32)s1[0]; fa.w[1] = (u32)s2[0];
                fa.w[2] = (u32)s1[1]; fa.w[3] = (u32)s2[1];
                bf16x8 bv0 = *(const bf16x8*)&vs_[vrd[0][jsub * 2 + ksub]];
                bf16x8 bv1 = *(const bf16x8*)&vs_[vrd[1][jsub * 2 + ksub]];
                o0 = __builtin_amdgcn_mfma_f32_32x32x16_bf16(fa.v, bv0, o0, 0, 0, 0);
                o1 = __builtin_amdgcn_mfma_f32_32x32x16_bf16(fa.v, bv1, o1, 0, 0, 0);
            }
        }
        ps += __shfl_xor(ps, 32);
        l_run += ps;
        if (t + 1 < njt) AT_STORE(cur ^ 1);
        __syncthreads();
    }
#undef AT_LOAD
#undef AT_STORE
}

// ---------------- fused main + aux attention (512 blocks -> 2 waves/SIMD)
__global__ __launch_bounds__(256)
void attn_fused(const u16* __restrict__ q_bf, const u16* __restrict__ kv,
                const u16* __restrict__ vTm_, const u16* __restrict__ ckv,
                const u16* __restrict__ vTc_, u16* __restrict__ out_bf,
                float* __restrict__ acc_sum) {
    __shared__ u16 k_s[2 * 4096];
    __shared__ u16 v_s[2 * 4096];
    __shared__ float red_s[4];
    const int id = blockIdx.x;
    const int tid = threadIdx.x;
    const int w = tid >> 6, lane = tid & 63;
    const int c31 = lane & 31, hi4 = (lane >> 5) << 2;

    if (id < 256) {
        const int it = id & 3, bh = id >> 2;
        const int b = bh >> 3, h = bh & 7;
        const int iwmin = it * 128 + w * 32;
        const int iq = iwmin + c31;

        bf16x8 qf[4];
#pragma unroll
        for (int ks = 0; ks < 4; ++ks)
            qf[ks] = *(const bf16x8*)&q_bf[(size_t)(b * TLEN + iq) * DMODEL + h * DH + ks * 16 + hi4 * 2];

        const u16* kbase = kv + (size_t)b * KVLEN * 1024 + h * DH;
        const u16* vbase = vTm_ + (size_t)(bh * DH) * KVLEN;
        const int njt = ((it * 128 + 767) >> 6) + 1;

        f32x16 o0 = {}, o1 = {};
        float m_run = -1e30f, l_run = 0.f;
        attn_pass<true>(kbase, 1024, vbase, KVLEN, njt, tid, iwmin, qf, k_s, v_s, o0, o1, m_run, l_run);

        float linv = 1.0f / l_run;
#pragma unroll
        for (int r = 0; r < 16; ++r) {
            int R = (r & 3) + 8 * (r >> 2) + hi4;
            float li = __shfl(linv, R);
            int i = iwmin + R;
            u16* o = out_bf + (size_t)(b * TLEN + i) * DMODEL + h * DH + c31;
            o[0]  = f2b(o0[r] * li);
            o[32] = f2b(o1[r] * li);
        }
    } else {
        const int t2 = id - 256;
        const int it = t2 & 3, bh = t2 >> 2;
        const int b = bh >> 3, h = bh & 7;
        const int iwmin = it * 128 + w * 32;
        const int iq = iwmin + c31;

        bf16x8 qf[4];
#pragma unroll
        for (int ks = 0; ks < 4; ++ks)
            qf[ks] = *(const bf16x8*)&q_bf[(size_t)(b * TLEN + iq) * DMODEL + h * DH + ks * 16 + hi4 * 2];

        f32x16 o0 = {}, o1 = {};
        float m_run = -1e30f, l_run = 0.f;
        attn_pass<false>(kv + (size_t)(b * KVLEN + 128) * 1024 + h * DH, 1024,
                         vTm_ + (size_t)(bh * DH) * KVLEN + 128, KVLEN, 8,
                         tid, 0, qf, k_s, v_s, o0, o1, m_run, l_run);
        float n0[16], n1[16];
        {
            float linv = 1.0f / l_run;
#pragma unroll
            for (int r = 0; r < 16; ++r) {
                float li = __shfl(linv, (r & 3) + 8 * (r >> 2) + hi4);
                n0[r] = o0[r] * li;
                n1[r] = o1[r] * li;
            }
        }
        f32x16 c0 = {}, c1 = {};
        m_run = -1e30f; l_run = 0.f;
        attn_pass<false>(ckv + (size_t)(b * 128) * 1024 + h * DH, 1024,
                         vTc_ + (size_t)(bh * DH) * 128, 128, 2,
                         tid, 0, qf, k_s, v_s, c0, c1, m_run, l_run);
        float lsum = 0.f;
        {
            float linv = 1.0f / l_run;
#pragma unroll
            for (int r = 0; r < 16; ++r) {
                float li = __shfl(linv, (r & 3) + 8 * (r >> 2) + hi4);
                float d0 = n0[r] - c0[r] * li;
                float d1 = n1[r] - c1[r] * li;
                lsum += d0 * d0 + d1 * d1;
            }
        }
        lsum = wave_red_sum(lsum);
        if (lane == 0) red_s[w] = lsum;
        __syncthreads();
        if (tid == 0) atomicAdd(acc_sum, red_s[0] + red_s[1] + red_s[2] + red_s[3]);
    }
}

// ---------------- fused tail: Wo GEMM + ae loss as MFMA GEMM w/ diff^2 epilogue + finalize
__global__ __launch_bounds__(256)
void tail2(const u16* __restrict__ attn_bf, const u16* __restrict__ wo_b,
           const float* __restrict__ bo, float* __restrict__ logits,
           const u16* __restrict__ dwb, const u16* __restrict__ compT,
           const float* __restrict__ mem, const float* __restrict__ db,
           float* __restrict__ accs, float* __restrict__ scal_out) {
    __shared__ __align__(16) char smem[16400];
    const int id = blockIdx.x;
    const int tid = threadIdx.x;
    u16* As = (u16*)smem;
    u16* Bs = (u16*)(smem + 8192);

    if (id < 128) {
        gemm_dev(attn_bf, 512, 4096, 0, wo_b, 512, 512,
                 nullptr, 0, logits, nullptr, 512, bo, id & 31, id >> 5, 0, As, Bs);
        return;
    }
    // ---- ae loss: recon = dw(512x128) x compT^T(512x128) per b, diff^2 vs mem
    float* red = (float*)(smem + 16384);
    const int t = id - 128;              // 0..127
    const int b = t >> 4;
    const int bx = (t >> 2) & 3, by = t & 3;
    const int lane = tid & 63, wave = tid >> 6;
    const int wr = (wave >> 1) * 64, wc = (wave & 1) * 64;
    const int fr = lane & 15, fg = lane >> 4;
    const int arow0 = bx * 128, brow0 = by * 128;
    const int lrow = lane >> 2, lcol = (lane & 3) * 8;
    const u16* gA[2]; const u16* gB[2];
#pragma unroll
    for (int i = 0; i < 2; ++i) {
        int r = wave * 32 + i * 16 + lrow;
        gA[i] = dwb + (size_t)(arow0 + r) * 128 + lcol;
        gB[i] = compT + (size_t)(b * 512 + brow0 + r) * 128 + lcol;
    }
    u16* lA0 = &As[(wave * 32) * 32];
    u16* lA1 = &As[(wave * 32 + 16) * 32];
    u16* lB0 = &Bs[(wave * 32) * 32];
    u16* lB1 = &Bs[(wave * 32 + 16) * 32];

    f32x4 acc[4][4] = {};
    for (int k = 0; k < 128; k += 32) {
        __syncthreads();
        gload16(gA[0] + k, lA0);
        gload16(gA[1] + k, lA1);
        gload16(gB[0] + k, lB0);
        gload16(gB[1] + k, lB1);
        __syncthreads();
        bf16x8 af[4], bfr[4];
#pragma unroll
        for (int m = 0; m < 4; ++m) af[m] = *(bf16x8*)&As[(wr + m * 16 + fr) * 32 + fg * 8];
#pragma unroll
        for (int n = 0; n < 4; ++n) bfr[n] = *(bf16x8*)&Bs[(wc + n * 16 + fr) * 32 + fg * 8];
#pragma unroll
        for (int m = 0; m < 4; ++m)
#pragma unroll
            for (int n = 0; n < 4; ++n)
                acc[m][n] = __builtin_amdgcn_mfma_f32_16x16x32_bf16(af[m], bfr[n], acc[m][n], 0, 0, 0);
    }

    float lsum = 0.f;
#pragma unroll
    for (int m = 0; m < 4; ++m)
#pragma unroll
        for (int n = 0; n < 4; ++n)
#pragma unroll
            for (int rr = 0; rr < 4; ++rr) {
                int row = arow0 + wr + m * 16 + fg * 4 + rr;   // mem row m
                int col = brow0 + wc + n * 16 + fr;            // dd
                float v = acc[m][n][rr] + db[row];
                float d = mem[(size_t)(b * 512 + row) * 512 + col] - v;
                lsum = fmaf(d, d, lsum);
            }
    lsum = wave_red_sum(lsum);
    if (lane == 0) red[wave] = lsum;
    __syncthreads();
    if (tid == 0) {
        atomicAdd(accs + 1, red[0] + red[1] + red[2] + red[3]);
        __threadfence();
        u32 c = atomicAdd((u32*)(accs + 2), 1u);
        if (c == 127u) {
            float a0 = atomicAdd(accs + 0, 0.f);
            float a1 = atomicAdd(accs + 1, 0.f);
            scal_out[0] = a0 * (1.f / 2097152.f);
            scal_out[1] = a1 * (1.f / 2097152.f);
        }
    }
}

// ---------------- launch ----------------
extern "C" void kernel_launch(void* const* d_in, const int* in_sizes, int n_in,
                              void* d_out, int out_size, void* d_ws, size_t ws_size,
                              hipStream_t stream) {
    const float* x      = (const float*)d_in[0];
    const float* mem    = (const float*)d_in[1];
    const float* cmem   = (const float*)d_in[2];
    const float* Wq     = (const float*)d_in[3];
    const float* Wkv    = (const float*)d_in[4];
    const float* Wo     = (const float*)d_in[5];
    const float* bo     = (const float*)d_in[6];
    const float* conv_w = (const float*)d_in[7];
    const float* conv_b = (const float*)d_in[8];
    const float* deconv_w = (const float*)d_in[9];
    const float* deconv_b = (const float*)d_in[10];
    float* out = (float*)d_out;

    char* w = (char*)d_ws;
    auto alloc = [&](size_t bytes) { char* p = w; w += (bytes + 255) & ~255ull; return p; };
    u16* Wq_bf   = (u16*)alloc(262144 * 2);
    u16* Wkv_bf  = (u16*)alloc(524288 * 2);
    u16* Wo_bf   = (u16*)alloc(262144 * 2);
    u16* cw2_bf  = (u16*)alloc(1048576 * 2);
    u16* dwb_bf  = (u16*)alloc(65536 * 2);
    u16* kvin_bf = (u16*)alloc(4718592 * 2);
    u16* q_bf    = (u16*)alloc(2097152 * 2);
    u16* kv_bf   = (u16*)alloc(9437184 * 2);
    u16* comp_bf = (u16*)alloc(524288 * 2);
    u16* compT   = (u16*)alloc(524288 * 2);
    u16* ckv_bf  = (u16*)alloc(1048576 * 2);
    u16* vTm     = (u16*)alloc(4718592 * 2);
    u16* vTc     = (u16*)alloc(524288 * 2);
    u16* attn_bf = (u16*)alloc(2097152 * 2);
    float* part  = (float*)alloc(4 * 524288 * 4);
    float* accs  = (float*)alloc(256);

    float* logits_o  = out;
    float* newmem_o  = out + 2097152;
    float* newcmem_o = out + 4194304;
    float* scalars_o = out + 4718592;

    // 1. prep: kvin + new_mem + weight converts (+deconv_w) + acc zero
    prep_kernel<<<6720, 256, 0, stream>>>(x, mem, cmem, Wq, Wkv, Wo, conv_w, deconv_w,
                                          kvin_bf, Wq_bf, Wkv_bf, Wo_bf, cw2_bf, dwb_bf,
                                          newmem_o, accs);

    // 2. fused q + kv + conv GEMMs (832 blocks, conv split-K=4)
    gemm3<<<832, 256, 0, stream>>>(kvin_bf, Wq_bf, Wkv_bf, cw2_bf, q_bf, kv_bf, part);

    // 3. conv split-K reduce -> new_cmem (f32) + comp (bf16)
    conv_reduce<<<512, 256, 0, stream>>>(part, conv_b, newcmem_o, comp_bf);

    // 4. mid: ckv GEMM + compT + vTm transposes (1344 blocks)
    mid_kernel<<<1344, 256, 0, stream>>>(comp_bf, Wkv_bf, ckv_bf, compT, kv_bf, vTm);

    // 5. vTc transpose (needs ckv)
    vtc_kernel<<<128, 256, 0, stream>>>(ckv_bf, vTc);

    // 6. fused main + aux attention
    attn_fused<<<512, 256, 0, stream>>>(q_bf, kv_bf, vTm, ckv_bf, vTc, attn_bf, accs);

    // 7. fused tail: Wo GEMM + ae-loss MFMA GEMM + finalize
    tail2<<<256, 256, 0, stream>>>(attn_bf, Wo_bf, bo, logits_o,
                                   dwb_bf, compT, mem, deconv_b,
                                   accs, scalars_o);
}